// Round 1
// baseline (206.574 us; speedup 1.0000x reference)
//
#include <hip/hip_runtime.h>
#include <hip/hip_bf16.h>

// Problem constants
#define BB   4
#define HH   32
#define QQ   16
#define NN   4096
#define HKV  8
#define DD   128
#define NK   3072
#define GRP  4

// ---------------------------------------------------------------------------
// Kernel 1: gather kept columns of attn_w, renormalize, write aw (output 2).
// grid = B*H*Q = 2048 blocks, 256 threads.
// ---------------------------------------------------------------------------
__global__ __launch_bounds__(256)
void k1_gather_norm(const float* __restrict__ attn_w,
                    const int* __restrict__ keep_idx,
                    float* __restrict__ aw_out)
{
    const int row = blockIdx.x;                 // (b*H + h)*Q + q
    const float* src = attn_w + (size_t)row * NN;
    float* dst = aw_out + (size_t)row * NK;

    __shared__ float vals[NK];
    __shared__ float red[256];

    float s = 0.f;
    for (int k = threadIdx.x; k < NK; k += 256) {
        float v = src[keep_idx[k]];
        vals[k] = v;
        s += v;
    }
    red[threadIdx.x] = s;
    __syncthreads();
    for (int st = 128; st > 0; st >>= 1) {
        if (threadIdx.x < st) red[threadIdx.x] += red[threadIdx.x + st];
        __syncthreads();
    }
    const float inv = 1.0f / (red[0] + 1e-6f);
    for (int k = threadIdx.x; k < NK; k += 256)
        dst[k] = vals[k] * inv;
}

// ---------------------------------------------------------------------------
// Kernel 2: partial ctx GEMM.  ctx[b,h,q,d] = sum_k aw[b,h,q,k]*V[b,h/4,idx[k],d]
// grid = B*HKV*SPLIT2 = 256 blocks, 256 threads (128 d-lanes x 2 row-halves).
// Each block covers 4 heads x 16 q = 64 rows so every V element feeds 64 FMAs
// (32 per thread; the two row-halves duplicate the V load, L1-hot).
// ---------------------------------------------------------------------------
#define SPLIT2 8
#define KPB    (NK / SPLIT2)   /* 384 */
#define CK     64

__global__ __launch_bounds__(256)
void k2_ctx(const float* __restrict__ aw,
            const float* __restrict__ v_cache,
            const int* __restrict__ keep_idx,
            float* __restrict__ partial)
{
    const int bid = blockIdx.x;
    const int s   = bid & 7;
    const int hkv = (bid >> 3) & 7;
    const int b   = bid >> 6;
    const int tid = threadIdx.x;
    const int d   = tid & 127;
    const int h2  = tid >> 7;      // row half (0/1): rows [h2*32, h2*32+32)

    // rows r = g*16+q are contiguous: global aw row = (b*H + hkv*4)*Q + r
    const float* awb = aw + (size_t)((b * HH + hkv * GRP) * QQ) * NK;
    const float* vb  = v_cache + (size_t)(b * HKV + hkv) * NN * DD;

    __shared__ float4 aw4[64][CK / 4];
    __shared__ int    idxs[CK];

    float acc[32];
#pragma unroll
    for (int i = 0; i < 32; ++i) acc[i] = 0.f;

    const int k0 = s * KPB;
    for (int c = 0; c < KPB; c += CK) {
        __syncthreads();
        if (tid < CK) idxs[tid] = keep_idx[k0 + c + tid];
        for (int i = tid; i < 64 * 16; i += 256) {
            int r  = i >> 4;
            int cc = i & 15;
            aw4[r][cc] = *reinterpret_cast<const float4*>(
                awb + (size_t)r * NK + k0 + c + cc * 4);
        }
        __syncthreads();

#pragma unroll 4
        for (int k4 = 0; k4 < CK / 4; ++k4) {
            const int i0 = idxs[k4 * 4 + 0];
            const int i1 = idxs[k4 * 4 + 1];
            const int i2 = idxs[k4 * 4 + 2];
            const int i3 = idxs[k4 * 4 + 3];
            const float v0 = vb[(size_t)i0 * DD + d];
            const float v1 = vb[(size_t)i1 * DD + d];
            const float v2 = vb[(size_t)i2 * DD + d];
            const float v3 = vb[(size_t)i3 * DD + d];
#pragma unroll
            for (int r = 0; r < 32; ++r) {
                // same address across all 64 lanes -> LDS broadcast (free)
                float4 a = aw4[h2 * 32 + r][k4];
                acc[r] += a.x * v0 + a.y * v1 + a.z * v2 + a.w * v3;
            }
        }
    }

    float* pb = partial + (size_t)bid * (64 * DD);
#pragma unroll
    for (int r = 0; r < 32; ++r)
        pb[(h2 * 32 + r) * DD + d] = acc[r];
}

// ---------------------------------------------------------------------------
// Kernel 3: reduce the 8 k-split partials into ctx[bq][i] (i = h*128+d),
// the [64][4096] layout the output GEMM wants.
// ---------------------------------------------------------------------------
__global__ __launch_bounds__(256)
void k3_reduce(const float* __restrict__ partial, float* __restrict__ ctx)
{
    const int flat = blockIdx.x * 256 + threadIdx.x;   // bq*4096 + i
    const int bq = flat >> 12;
    const int i  = flat & 4095;
    const int b = bq >> 4, q = bq & 15;
    const int h = i >> 7,  d = i & 127;
    const int hkv = h >> 2, g = h & 3;
    const int r = g * 16 + q;

    const float* p = partial + (size_t)((b * 8 + hkv) * 8) * (64 * DD) + r * DD + d;
    float s = 0.f;
#pragma unroll
    for (int ss = 0; ss < 8; ++ss) s += p[(size_t)ss * (64 * DD)];
    ctx[flat] = s;
}

// ---------------------------------------------------------------------------
// Kernel 4: out = ctx @ W^T, M=64 (bq) x N=4096 (o) x K=4096.
// grid = 64 o-tiles * 8 k-splits = 512 blocks, 256 threads.
// Tile 64o x 64bq, 4x4 register blocking per thread (o,bq strided by 16).
// ---------------------------------------------------------------------------
#define KSPLIT4 8
#define K4LEN   (4096 / KSPLIT4)  /* 512 */
#define KC      64

__global__ __launch_bounds__(256)
void k4_gemm(const float* __restrict__ ctx,
             const float* __restrict__ W,
             float* __restrict__ pout)
{
    const int ot  = blockIdx.x >> 3;   // 0..63
    const int ks  = blockIdx.x & 7;
    const int tid = threadIdx.x;
    const int ol  = tid & 15;          // o rows ol + 16*j
    const int bql = tid >> 4;          // bq rows bql + 16*i

    __shared__ float Cl[64][68];
    __shared__ float Wl[64][68];

    float acc[4][4];
#pragma unroll
    for (int i = 0; i < 4; ++i)
#pragma unroll
        for (int j = 0; j < 4; ++j) acc[i][j] = 0.f;

    const float* Wb = W + (size_t)(ot * 64) * 4096;
    const int kbase0 = ks * K4LEN;

    for (int kc = 0; kc < K4LEN; kc += KC) {
        const int kb = kbase0 + kc;
        __syncthreads();
        for (int i2 = tid; i2 < 64 * 16; i2 += 256) {
            int r  = i2 >> 4;
            int cc = i2 & 15;
            float4 cv = *reinterpret_cast<const float4*>(ctx + (size_t)r * 4096 + kb + cc * 4);
            *reinterpret_cast<float4*>(&Cl[r][cc * 4]) = cv;
            float4 wv = *reinterpret_cast<const float4*>(Wb + (size_t)r * 4096 + kb + cc * 4);
            *reinterpret_cast<float4*>(&Wl[r][cc * 4]) = wv;
        }
        __syncthreads();

#pragma unroll
        for (int k4 = 0; k4 < KC / 4; ++k4) {
            float4 w[4], c[4];
#pragma unroll
            for (int j = 0; j < 4; ++j)
                w[j] = *reinterpret_cast<const float4*>(&Wl[ol + 16 * j][k4 * 4]);
#pragma unroll
            for (int i = 0; i < 4; ++i)
                c[i] = *reinterpret_cast<const float4*>(&Cl[bql + 16 * i][k4 * 4]);
#pragma unroll
            for (int i = 0; i < 4; ++i)
#pragma unroll
                for (int j = 0; j < 4; ++j)
                    acc[i][j] += c[i].x * w[j].x + c[i].y * w[j].y +
                                 c[i].z * w[j].z + c[i].w * w[j].w;
        }
    }

    float* pb = pout + (size_t)ks * (64 * 4096);
#pragma unroll
    for (int i = 0; i < 4; ++i)
#pragma unroll
        for (int j = 0; j < 4; ++j)
            pb[(size_t)(bql + 16 * i) * 4096 + ot * 64 + ol + 16 * j] = acc[i][j];
}

// ---------------------------------------------------------------------------
// Kernel 5: reduce the 8 k-split output partials -> out (output 1).
// ---------------------------------------------------------------------------
__global__ __launch_bounds__(256)
void k5_out(const float* __restrict__ pout, float* __restrict__ out)
{
    const int flat = blockIdx.x * 256 + threadIdx.x;
    float s = 0.f;
#pragma unroll
    for (int ss = 0; ss < 8; ++ss) s += pout[(size_t)ss * (64 * 4096) + flat];
    out[flat] = s;
}

// ---------------------------------------------------------------------------
extern "C" void kernel_launch(void* const* d_in, const int* in_sizes, int n_in,
                              void* d_out, int out_size, void* d_ws, size_t ws_size,
                              hipStream_t stream)
{
    const float* attn_w  = (const float*)d_in[0];   // [4][32][16][4096]
    const float* v_cache = (const float*)d_in[1];   // [4][8][4096][128]
    const float* o_proj  = (const float*)d_in[2];   // [4096][4096]
    const int*   keep_idx = (const int*)d_in[3];    // [3072]

    float* out    = (float*)d_out;                  // [4][16][4096] = 262144
    float* aw_out = (float*)d_out + 262144;         // [4][32][16][3072] = 6291456

    float* ws       = (float*)d_ws;
    float* partial2 = ws;                 // 2,097,152 floats (8 MB)
    float* ctx      = ws + 2097152;       //   262,144 floats (1 MB)
    float* pout     = ws;                 // reuse partial2 region (dead after k3)

    k1_gather_norm<<<BB * HH * QQ, 256, 0, stream>>>(attn_w, keep_idx, aw_out);
    k2_ctx<<<BB * HKV * SPLIT2, 256, 0, stream>>>(aw_out, v_cache, keep_idx, partial2);
    k3_reduce<<<(64 * 4096) / 256, 256, 0, stream>>>(partial2, ctx);
    k4_gemm<<<64 * KSPLIT4, 256, 0, stream>>>(ctx, o_proj, pout);
    k5_out<<<(64 * 4096) / 256, 256, 0, stream>>>(pout, out);
}

// Round 2
// 123.723 us; speedup vs baseline: 1.6696x; 1.6696x over previous
//
#include <hip/hip_runtime.h>
#include <hip/hip_bf16.h>

// Problem constants
#define BB   4
#define HH   32
#define QQ   16
#define NN   4096
#define HKV  8
#define DD   128
#define NK   3072
#define GRP  4

// ---------------------------------------------------------------------------
// Kernel 1: gather kept columns of attn_w, renormalize, write aw (output 2).
// grid = B*H*Q = 2048 blocks, 256 threads.
// ---------------------------------------------------------------------------
__global__ __launch_bounds__(256)
void k1_gather_norm(const float* __restrict__ attn_w,
                    const int* __restrict__ keep_idx,
                    float* __restrict__ aw_out)
{
    const int row = blockIdx.x;                 // (b*H + h)*Q + q
    const float* src = attn_w + (size_t)row * NN;
    float* dst = aw_out + (size_t)row * NK;

    __shared__ float vals[NK];
    __shared__ float red[256];

    float s = 0.f;
    for (int k = threadIdx.x; k < NK; k += 256) {
        float v = src[keep_idx[k]];
        vals[k] = v;
        s += v;
    }
    red[threadIdx.x] = s;
    __syncthreads();
    for (int st = 128; st > 0; st >>= 1) {
        if (threadIdx.x < st) red[threadIdx.x] += red[threadIdx.x + st];
        __syncthreads();
    }
    const float inv = 1.0f / (red[0] + 1e-6f);
    for (int k = threadIdx.x; k < NK; k += 256)
        dst[k] = vals[k] * inv;
}

// ---------------------------------------------------------------------------
// Kernel 2 (v2): partial ctx GEMM, occupancy-fixed.
//   ctx[b,h,q,d] = sum_k aw[b,h,q,k] * V[b,h/4,idx[k],d]
// grid = B*HKV*SPLITK2 = 4*8*16 = 512 blocks, 256 threads.
// Thread = (rg, dl): rg = row-group (8 rows of the 64 (g,q) rows), dl = d/4
// lane (float4 over d). Each ds_read_b128 of aw feeds 16 FMAs.
// K-ranges disjoint across blocks -> aw and V each read exactly once.
// Partials stored bf16 so 16 splits fit in 8 MB of workspace.
// ---------------------------------------------------------------------------
#define SPLITK2 16
#define KPB2    (NK / SPLITK2)   /* 192 */
#define CK2     64

__global__ __launch_bounds__(256)
void k2_ctx(const float* __restrict__ aw,
            const float* __restrict__ v_cache,
            const int* __restrict__ keep_idx,
            __hip_bfloat16* __restrict__ partial)
{
    const int bid = blockIdx.x;          // ((b*8+hkv)*16 + ks)
    const int ks  = bid & 15;
    const int hkv = (bid >> 4) & 7;
    const int b   = bid >> 7;
    const int tid = threadIdx.x;
    const int dl  = tid & 31;            // d = 4*dl .. 4*dl+3
    const int rg  = tid >> 5;            // rows rg*8 .. rg*8+7

    const float* awb = aw + (size_t)((b * HH + hkv * GRP) * QQ) * NK;
    const float* vb  = v_cache + (size_t)(b * HKV + hkv) * NN * DD;

    __shared__ float awt[64][CK2];       // 16 KB
    alignas(16) __shared__ int idxs[CK2];

    float4 acc[8];
#pragma unroll
    for (int r = 0; r < 8; ++r) acc[r] = make_float4(0.f, 0.f, 0.f, 0.f);

    const int k0 = ks * KPB2;
    for (int c = 0; c < KPB2; c += CK2) {
        __syncthreads();
        if (tid < CK2) idxs[tid] = keep_idx[k0 + c + tid];
        for (int i = tid; i < 64 * (CK2 / 4); i += 256) {   // 1024 float4s
            int r  = i >> 4;
            int cc = i & 15;
            *reinterpret_cast<float4*>(&awt[r][cc * 4]) =
                *reinterpret_cast<const float4*>(awb + (size_t)r * NK + k0 + c + cc * 4);
        }
        __syncthreads();

#pragma unroll
        for (int k4 = 0; k4 < CK2 / 4; ++k4) {
            const int4 ii = *reinterpret_cast<const int4*>(&idxs[k4 * 4]);
            const float4 v0 = *reinterpret_cast<const float4*>(vb + (size_t)ii.x * DD + dl * 4);
            const float4 v1 = *reinterpret_cast<const float4*>(vb + (size_t)ii.y * DD + dl * 4);
            const float4 v2 = *reinterpret_cast<const float4*>(vb + (size_t)ii.z * DD + dl * 4);
            const float4 v3 = *reinterpret_cast<const float4*>(vb + (size_t)ii.w * DD + dl * 4);
#pragma unroll
            for (int r = 0; r < 8; ++r) {
                const float4 a = *reinterpret_cast<const float4*>(&awt[rg * 8 + r][k4 * 4]);
                acc[r].x += a.x * v0.x + a.y * v1.x + a.z * v2.x + a.w * v3.x;
                acc[r].y += a.x * v0.y + a.y * v1.y + a.z * v2.y + a.w * v3.y;
                acc[r].z += a.x * v0.z + a.y * v1.z + a.z * v2.z + a.w * v3.z;
                acc[r].w += a.x * v0.w + a.y * v1.w + a.z * v2.w + a.w * v3.w;
            }
        }
    }

    // partial layout: [bid][64][128] in bf16
    __hip_bfloat16* pb = partial + (size_t)bid * (64 * DD);
#pragma unroll
    for (int r = 0; r < 8; ++r) {
        const int row = rg * 8 + r;
        union { ushort4 u; __hip_bfloat16 h[4]; } pk;
        pk.h[0] = __float2bfloat16(acc[r].x);
        pk.h[1] = __float2bfloat16(acc[r].y);
        pk.h[2] = __float2bfloat16(acc[r].z);
        pk.h[3] = __float2bfloat16(acc[r].w);
        *reinterpret_cast<ushort4*>(pb + row * DD + dl * 4) = pk.u;
    }
}

// ---------------------------------------------------------------------------
// Kernel 3: reduce the 16 bf16 k-split partials into ctx[bq][i] (i = h*128+d),
// the [64][4096] layout the output GEMM wants.
// ---------------------------------------------------------------------------
__global__ __launch_bounds__(256)
void k3_reduce(const __hip_bfloat16* __restrict__ partial, float* __restrict__ ctx)
{
    const int flat = blockIdx.x * 256 + threadIdx.x;   // bq*4096 + i
    const int bq = flat >> 12;
    const int i  = flat & 4095;
    const int b = bq >> 4, q = bq & 15;
    const int h = i >> 7,  d = i & 127;
    const int hkv = h >> 2, g = h & 3;
    const int r = g * 16 + q;

    const __hip_bfloat16* p = partial
        + (size_t)((b * 8 + hkv) * SPLITK2) * (64 * DD) + r * DD + d;
    float s = 0.f;
#pragma unroll
    for (int ss = 0; ss < SPLITK2; ++ss)
        s += __bfloat162float(p[(size_t)ss * (64 * DD)]);
    ctx[flat] = s;
}

// ---------------------------------------------------------------------------
// Kernel 4: out = ctx @ W^T, M=64 (bq) x N=4096 (o) x K=4096.
// grid = 64 o-tiles * 8 k-splits = 512 blocks, 256 threads.
// Tile 64o x 64bq, 4x4 register blocking per thread (o,bq strided by 16).
// ---------------------------------------------------------------------------
#define KSPLIT4 8
#define K4LEN   (4096 / KSPLIT4)  /* 512 */
#define KC      64

__global__ __launch_bounds__(256)
void k4_gemm(const float* __restrict__ ctx,
             const float* __restrict__ W,
             float* __restrict__ pout)
{
    const int ot  = blockIdx.x >> 3;   // 0..63
    const int ks  = blockIdx.x & 7;
    const int tid = threadIdx.x;
    const int ol  = tid & 15;          // o rows ol + 16*j
    const int bql = tid >> 4;          // bq rows bql + 16*i

    __shared__ float Cl[64][68];
    __shared__ float Wl[64][68];

    float acc[4][4];
#pragma unroll
    for (int i = 0; i < 4; ++i)
#pragma unroll
        for (int j = 0; j < 4; ++j) acc[i][j] = 0.f;

    const float* Wb = W + (size_t)(ot * 64) * 4096;
    const int kbase0 = ks * K4LEN;

    for (int kc = 0; kc < K4LEN; kc += KC) {
        const int kb = kbase0 + kc;
        __syncthreads();
        for (int i2 = tid; i2 < 64 * 16; i2 += 256) {
            int r  = i2 >> 4;
            int cc = i2 & 15;
            float4 cv = *reinterpret_cast<const float4*>(ctx + (size_t)r * 4096 + kb + cc * 4);
            *reinterpret_cast<float4*>(&Cl[r][cc * 4]) = cv;
            float4 wv = *reinterpret_cast<const float4*>(Wb + (size_t)r * 4096 + kb + cc * 4);
            *reinterpret_cast<float4*>(&Wl[r][cc * 4]) = wv;
        }
        __syncthreads();

#pragma unroll
        for (int k4 = 0; k4 < KC / 4; ++k4) {
            float4 w[4], c[4];
#pragma unroll
            for (int j = 0; j < 4; ++j)
                w[j] = *reinterpret_cast<const float4*>(&Wl[ol + 16 * j][k4 * 4]);
#pragma unroll
            for (int i = 0; i < 4; ++i)
                c[i] = *reinterpret_cast<const float4*>(&Cl[bql + 16 * i][k4 * 4]);
#pragma unroll
            for (int i = 0; i < 4; ++i)
#pragma unroll
                for (int j = 0; j < 4; ++j)
                    acc[i][j] += c[i].x * w[j].x + c[i].y * w[j].y +
                                 c[i].z * w[j].z + c[i].w * w[j].w;
        }
    }

    float* pb = pout + (size_t)ks * (64 * 4096);
#pragma unroll
    for (int i = 0; i < 4; ++i)
#pragma unroll
        for (int j = 0; j < 4; ++j)
            pb[(size_t)(bql + 16 * i) * 4096 + ot * 64 + ol + 16 * j] = acc[i][j];
}

// ---------------------------------------------------------------------------
// Kernel 5: reduce the 8 k-split output partials -> out (output 1).
// ---------------------------------------------------------------------------
__global__ __launch_bounds__(256)
void k5_out(const float* __restrict__ pout, float* __restrict__ out)
{
    const int flat = blockIdx.x * 256 + threadIdx.x;
    float s = 0.f;
#pragma unroll
    for (int ss = 0; ss < 8; ++ss) s += pout[(size_t)ss * (64 * 4096) + flat];
    out[flat] = s;
}

// ---------------------------------------------------------------------------
extern "C" void kernel_launch(void* const* d_in, const int* in_sizes, int n_in,
                              void* d_out, int out_size, void* d_ws, size_t ws_size,
                              hipStream_t stream)
{
    const float* attn_w  = (const float*)d_in[0];   // [4][32][16][4096]
    const float* v_cache = (const float*)d_in[1];   // [4][8][4096][128]
    const float* o_proj  = (const float*)d_in[2];   // [4096][4096]
    const int*   keep_idx = (const int*)d_in[3];    // [3072]

    float* out    = (float*)d_out;                  // [4][16][4096] = 262144
    float* aw_out = (float*)d_out + 262144;         // [4][32][16][3072] = 6291456

    // ws layout (bytes):
    //   [0, 8 MB)        : k2 bf16 partial (4,194,304 bf16)  -- dead after k3
    //   [0, 8 MB)        : k4 fp32 pout (2,097,152 f32)      -- reuses region
    //   [8 MB, 9 MB)     : ctx fp32 (262,144 f32)
    __hip_bfloat16* partial2 = (__hip_bfloat16*)d_ws;
    float* ctx  = (float*)((char*)d_ws + (size_t)8 * 1024 * 1024);
    float* pout = (float*)d_ws;

    k1_gather_norm<<<BB * HH * QQ, 256, 0, stream>>>(attn_w, keep_idx, aw_out);
    k2_ctx<<<BB * HKV * SPLITK2, 256, 0, stream>>>(aw_out, v_cache, keep_idx, partial2);
    k3_reduce<<<(64 * 4096) / 256, 256, 0, stream>>>(partial2, ctx);
    k4_gemm<<<64 * KSPLIT4, 256, 0, stream>>>(ctx, o_proj, pout);
    k5_out<<<(64 * 4096) / 256, 256, 0, stream>>>(pout, out);
}

// Round 3
// 67.037 us; speedup vs baseline: 3.0815x; 1.8456x over previous
//
#include <hip/hip_runtime.h>
#include <hip/hip_bf16.h>

// Problem constants
#define BB   4
#define HH   32
#define QQ   16
#define NN   4096
#define HKV  8
#define DD   128
#define NK   3072
#define GRP  4

typedef __attribute__((ext_vector_type(8))) short bf16x8;
typedef __attribute__((ext_vector_type(4))) float f32x4;

// ---------------------------------------------------------------------------
// Kernel 1: gather kept columns of attn_w, renormalize, write aw (output 2).
// grid = B*H*Q = 2048 blocks, 256 threads.
// ---------------------------------------------------------------------------
__global__ __launch_bounds__(256)
void k1_gather_norm(const float* __restrict__ attn_w,
                    const int* __restrict__ keep_idx,
                    float* __restrict__ aw_out)
{
    const int row = blockIdx.x;                 // (b*H + h)*Q + q
    const float* src = attn_w + (size_t)row * NN;
    float* dst = aw_out + (size_t)row * NK;

    __shared__ float vals[NK];
    __shared__ float red[256];

    float s = 0.f;
    for (int k = threadIdx.x; k < NK; k += 256) {
        float v = src[keep_idx[k]];
        vals[k] = v;
        s += v;
    }
    red[threadIdx.x] = s;
    __syncthreads();
    for (int st = 128; st > 0; st >>= 1) {
        if (threadIdx.x < st) red[threadIdx.x] += red[threadIdx.x + st];
        __syncthreads();
    }
    const float inv = 1.0f / (red[0] + 1e-6f);
    for (int k = threadIdx.x; k < NK; k += 256)
        dst[k] = vals[k] * inv;
}

// ---------------------------------------------------------------------------
// Kernel 2: partial ctx GEMM (occupancy-fixed, round-1 version, unchanged).
// grid = B*HKV*SPLITK2 = 512 blocks, 256 threads.
// ---------------------------------------------------------------------------
#define SPLITK2 16
#define KPB2    (NK / SPLITK2)   /* 192 */
#define CK2     64

__global__ __launch_bounds__(256)
void k2_ctx(const float* __restrict__ aw,
            const float* __restrict__ v_cache,
            const int* __restrict__ keep_idx,
            __hip_bfloat16* __restrict__ partial)
{
    const int bid = blockIdx.x;          // ((b*8+hkv)*16 + ks)
    const int ks  = bid & 15;
    const int hkv = (bid >> 4) & 7;
    const int b   = bid >> 7;
    const int tid = threadIdx.x;
    const int dl  = tid & 31;            // d = 4*dl .. 4*dl+3
    const int rg  = tid >> 5;            // rows rg*8 .. rg*8+7

    const float* awb = aw + (size_t)((b * HH + hkv * GRP) * QQ) * NK;
    const float* vb  = v_cache + (size_t)(b * HKV + hkv) * NN * DD;

    __shared__ float awt[64][CK2];       // 16 KB
    alignas(16) __shared__ int idxs[CK2];

    float4 acc[8];
#pragma unroll
    for (int r = 0; r < 8; ++r) acc[r] = make_float4(0.f, 0.f, 0.f, 0.f);

    const int k0 = ks * KPB2;
    for (int c = 0; c < KPB2; c += CK2) {
        __syncthreads();
        if (tid < CK2) idxs[tid] = keep_idx[k0 + c + tid];
        for (int i = tid; i < 64 * (CK2 / 4); i += 256) {   // 1024 float4s
            int r  = i >> 4;
            int cc = i & 15;
            *reinterpret_cast<float4*>(&awt[r][cc * 4]) =
                *reinterpret_cast<const float4*>(awb + (size_t)r * NK + k0 + c + cc * 4);
        }
        __syncthreads();

#pragma unroll
        for (int k4 = 0; k4 < CK2 / 4; ++k4) {
            const int4 ii = *reinterpret_cast<const int4*>(&idxs[k4 * 4]);
            const float4 v0 = *reinterpret_cast<const float4*>(vb + (size_t)ii.x * DD + dl * 4);
            const float4 v1 = *reinterpret_cast<const float4*>(vb + (size_t)ii.y * DD + dl * 4);
            const float4 v2 = *reinterpret_cast<const float4*>(vb + (size_t)ii.z * DD + dl * 4);
            const float4 v3 = *reinterpret_cast<const float4*>(vb + (size_t)ii.w * DD + dl * 4);
#pragma unroll
            for (int r = 0; r < 8; ++r) {
                const float4 a = *reinterpret_cast<const float4*>(&awt[rg * 8 + r][k4 * 4]);
                acc[r].x += a.x * v0.x + a.y * v1.x + a.z * v2.x + a.w * v3.x;
                acc[r].y += a.x * v0.y + a.y * v1.y + a.z * v2.y + a.w * v3.y;
                acc[r].z += a.x * v0.z + a.y * v1.z + a.z * v2.z + a.w * v3.z;
                acc[r].w += a.x * v0.w + a.y * v1.w + a.z * v2.w + a.w * v3.w;
            }
        }
    }

    // partial layout: [bid][64][128] in bf16
    __hip_bfloat16* pb = partial + (size_t)bid * (64 * DD);
#pragma unroll
    for (int r = 0; r < 8; ++r) {
        const int row = rg * 8 + r;
        union { ushort4 u; __hip_bfloat16 h[4]; } pk;
        pk.h[0] = __float2bfloat16(acc[r].x);
        pk.h[1] = __float2bfloat16(acc[r].y);
        pk.h[2] = __float2bfloat16(acc[r].z);
        pk.h[3] = __float2bfloat16(acc[r].w);
        *reinterpret_cast<ushort4*>(pb + row * DD + dl * 4) = pk.u;
    }
}

// ---------------------------------------------------------------------------
// Kernel 3: reduce the 16 bf16 k-split partials into ctx_b[bq][i] (i=h*128+d)
// in BF16 -- the MFMA A-operand layout for k4.
// ---------------------------------------------------------------------------
__global__ __launch_bounds__(256)
void k3_reduce(const __hip_bfloat16* __restrict__ partial,
               __hip_bfloat16* __restrict__ ctxb)
{
    const int flat = blockIdx.x * 256 + threadIdx.x;   // bq*4096 + i
    const int bq = flat >> 12;
    const int i  = flat & 4095;
    const int b = bq >> 4, q = bq & 15;
    const int h = i >> 7,  d = i & 127;
    const int hkv = h >> 2, g = h & 3;
    const int r = g * 16 + q;

    const __hip_bfloat16* p = partial
        + (size_t)((b * 8 + hkv) * SPLITK2) * (64 * DD) + r * DD + d;
    float s = 0.f;
#pragma unroll
    for (int ss = 0; ss < SPLITK2; ++ss)
        s += __bfloat162float(p[(size_t)ss * (64 * DD)]);
    ctxb[flat] = __float2bfloat16(s);
}

// ---------------------------------------------------------------------------
// Kernel 4 (v2): out = ctx @ W^T via bf16 MFMA, M=64 x N=4096 x K=4096.
// grid = 128 N-tiles (32 o-cols) * 8 k-splits = 1024 blocks (4/CU), 256 thr.
// Per block: K-chunks of 128; stage ctx_b (bf16 copy) and W (f32->bf16 cvt)
// into row-major padded LDS; 4 waves each own 16 M-rows x 32 N-cols
// (2 MFMA tiles), mfma_f32_16x16x32_bf16, f32 accum.
// Fragment layout (m92-verified pattern): A row = lane&15, k = (lane>>4)*8+e
// contiguous; B(T) col = lane&15, same k slice; C/D col=lane&15,
// row=(lane>>4)*4+reg.
// ---------------------------------------------------------------------------
#define K4SPLIT 8
#define K4LEN   (4096 / K4SPLIT)  /* 512 */
#define KC4     128
#define LPAD    136               /* 128 + 8 ushort pad: fragment reads <=2-way bank alias */

__global__ __launch_bounds__(256)
void k4_gemm(const __hip_bfloat16* __restrict__ ctxb,
             const float* __restrict__ W,
             float* __restrict__ pout)
{
    const int nt  = blockIdx.x >> 3;   // 0..127  (o-cols nt*32 .. nt*32+31)
    const int ks  = blockIdx.x & 7;
    const int tid = threadIdx.x;
    const int lane = tid & 63;
    const int w    = tid >> 6;         // wave id: M-rows w*16 .. w*16+15

    __shared__ unsigned short Al[64][LPAD];   // ctx bf16 tile, 17408 B
    __shared__ unsigned short Bl[32][LPAD];   // W   bf16 tile,  8704 B

    f32x4 acc0 = {0.f, 0.f, 0.f, 0.f};
    f32x4 acc1 = {0.f, 0.f, 0.f, 0.f};

    const unsigned short* ctxu = reinterpret_cast<const unsigned short*>(ctxb);
    const int kbase = ks * K4LEN;
    const int fr = lane & 15;          // fragment row/col
    const int kg = lane >> 4;          // k-group (8 bf16 each)

    for (int ch = 0; ch < K4LEN / KC4; ++ch) {
        const int kb = kbase + ch * KC4;
        __syncthreads();

        // stage A: 64 rows x 128 bf16 (16B/thread x 4 passes)
        {
            const int cc = tid & 15;       // 8-ushort chunk within row
            const int r0 = tid >> 4;       // 16 rows per pass
#pragma unroll
            for (int p = 0; p < 4; ++p) {
                const int r = r0 + p * 16;
                float4 v = *reinterpret_cast<const float4*>(
                    ctxu + (size_t)r * 4096 + kb + cc * 8);
                *reinterpret_cast<float4*>(&Al[r][cc * 8]) = v;
            }
        }
        // stage B: 32 rows x 128 f32 -> bf16 (float4/thread x 4 passes)
        {
            const int cc = tid & 31;       // float4 col
            const int r0 = tid >> 5;       // 8 rows per pass
#pragma unroll
            for (int p = 0; p < 4; ++p) {
                const int r = r0 + p * 8;
                float4 v = *reinterpret_cast<const float4*>(
                    W + (size_t)(nt * 32 + r) * 4096 + kb + cc * 4);
                union { ushort4 u; __hip_bfloat16 h[4]; } pk;
                pk.h[0] = __float2bfloat16(v.x);
                pk.h[1] = __float2bfloat16(v.y);
                pk.h[2] = __float2bfloat16(v.z);
                pk.h[3] = __float2bfloat16(v.w);
                *reinterpret_cast<ushort4*>(&Bl[r][cc * 4]) = pk.u;
            }
        }
        __syncthreads();

#pragma unroll
        for (int kst = 0; kst < KC4 / 32; ++kst) {
            const int ko = kst * 32 + kg * 8;
            bf16x8 a  = *reinterpret_cast<const bf16x8*>(&Al[w * 16 + fr][ko]);
            bf16x8 b0 = *reinterpret_cast<const bf16x8*>(&Bl[fr][ko]);
            bf16x8 b1 = *reinterpret_cast<const bf16x8*>(&Bl[16 + fr][ko]);
            acc0 = __builtin_amdgcn_mfma_f32_16x16x32_bf16(a, b0, acc0, 0, 0, 0);
            acc1 = __builtin_amdgcn_mfma_f32_16x16x32_bf16(a, b1, acc1, 0, 0, 0);
        }
    }

    // epilogue: C/D layout col=lane&15, row=(lane>>4)*4+reg
    float* pb = pout + (size_t)ks * (64 * 4096);
#pragma unroll
    for (int reg = 0; reg < 4; ++reg) {
        const int row = w * 16 + kg * 4 + reg;
        pb[(size_t)row * 4096 + nt * 32 + fr]      = acc0[reg];
        pb[(size_t)row * 4096 + nt * 32 + 16 + fr] = acc1[reg];
    }
}

// ---------------------------------------------------------------------------
// Kernel 5: reduce the 8 k-split output partials -> out (output 1).
// ---------------------------------------------------------------------------
__global__ __launch_bounds__(256)
void k5_out(const float* __restrict__ pout, float* __restrict__ out)
{
    const int flat = blockIdx.x * 256 + threadIdx.x;
    float s = 0.f;
#pragma unroll
    for (int ss = 0; ss < K4SPLIT; ++ss)
        s += pout[(size_t)ss * (64 * 4096) + flat];
    out[flat] = s;
}

// ---------------------------------------------------------------------------
extern "C" void kernel_launch(void* const* d_in, const int* in_sizes, int n_in,
                              void* d_out, int out_size, void* d_ws, size_t ws_size,
                              hipStream_t stream)
{
    const float* attn_w  = (const float*)d_in[0];   // [4][32][16][4096]
    const float* v_cache = (const float*)d_in[1];   // [4][8][4096][128]
    const float* o_proj  = (const float*)d_in[2];   // [4096][4096]
    const int*   keep_idx = (const int*)d_in[3];    // [3072]

    float* out    = (float*)d_out;                  // [4][16][4096] = 262144
    float* aw_out = (float*)d_out + 262144;         // [4][32][16][3072] = 6291456

    // ws layout (bytes):
    //   [0, 8 MB)      : k2 bf16 partial (4,194,304 bf16)  -- dead after k3
    //   [0, 8 MB)      : k4 fp32 pout (2,097,152 f32)      -- reuses region
    //   [8 MB, 8.5 MB) : ctx bf16 (262,144 bf16)
    __hip_bfloat16* partial2 = (__hip_bfloat16*)d_ws;
    __hip_bfloat16* ctxb = (__hip_bfloat16*)((char*)d_ws + (size_t)8 * 1024 * 1024);
    float* pout = (float*)d_ws;

    k1_gather_norm<<<BB * HH * QQ, 256, 0, stream>>>(attn_w, keep_idx, aw_out);
    k2_ctx<<<BB * HKV * SPLITK2, 256, 0, stream>>>(aw_out, v_cache, keep_idx, partial2);
    k3_reduce<<<(64 * 4096) / 256, 256, 0, stream>>>(partial2, ctxb);
    k4_gemm<<<128 * K4SPLIT, 256, 0, stream>>>(ctxb, o_proj, pout);
    k5_out<<<(64 * 4096) / 256, 256, 0, stream>>>(pout, out);
}

// Round 5
// 48.883 us; speedup vs baseline: 4.2259x; 1.3714x over previous
//
#include <hip/hip_runtime.h>
#include <hip/hip_bf16.h>

// Problem constants
#define BB   4
#define HH   32
#define QQ   16
#define NN   4096
#define HKV  8
#define DD   128
#define NK   3072
#define GRP  4

typedef __attribute__((ext_vector_type(8))) short bf16x8;
typedef __attribute__((ext_vector_type(4))) float f32x4;

__device__ __forceinline__ unsigned int pack_bf16(float lo, float hi) {
    union { unsigned int u; __hip_bfloat16 h[2]; } p;
    p.h[0] = __float2bfloat16(lo);
    p.h[1] = __float2bfloat16(hi);
    return p.u;
}

// ---------------------------------------------------------------------------
// Kernel 1: gather kept columns of attn_w, renormalize, write aw (output 2).
// grid = B*H*Q = 2048 blocks, 256 threads.
// ---------------------------------------------------------------------------
__global__ __launch_bounds__(256)
void k1_gather_norm(const float* __restrict__ attn_w,
                    const int* __restrict__ keep_idx,
                    float* __restrict__ aw_out)
{
    const int row = blockIdx.x;                 // (b*H + h)*Q + q
    const float* src = attn_w + (size_t)row * NN;
    float* dst = aw_out + (size_t)row * NK;

    __shared__ float vals[NK];
    __shared__ float red[256];

    float s = 0.f;
    for (int k = threadIdx.x; k < NK; k += 256) {
        float v = src[keep_idx[k]];
        vals[k] = v;
        s += v;
    }
    red[threadIdx.x] = s;
    __syncthreads();
    for (int st = 128; st > 0; st >>= 1) {
        if (threadIdx.x < st) red[threadIdx.x] += red[threadIdx.x + st];
        __syncthreads();
    }
    const float inv = 1.0f / (red[0] + 1e-6f);
    for (int k = threadIdx.x; k < NK; k += 256)
        dst[k] = vals[k] * inv;
}

// ---------------------------------------------------------------------------
// Kernel 2 (v4): ctx partial GEMM via bf16 MFMA.
//   ctx[b,h,q,d] = sum_k aw[b,h,q,k] * V[b,h/4,idx[k],d]
// grid = B*HKV*SPLITK2 = 512 blocks, 256 threads (4 waves).
// Per block: M=64 aw rows (4 heads x 16 q), N=128 (d), K=192 gathered rows,
// in 3 chunks of 64. Wave w owns M-rows w*16..w*16+15, all 8 N-tiles.
//   A: global f32 -> in-register bf16x8 fragments (rows wave-exclusive).
//   B: gathered V staged transposed into LDS Vt[d][k] bf16, XOR chunk swizzle
//      us(d,cs) = d*64 + ((cs ^ (d&7))<<3), cs = 16B chunk (8 k) 0..7.
//      STAGING COVERAGE (round-3 bug fix): unit = (d,cs) -> 128*8 = 1024
//      units = 4 passes x 256 threads, exactly the full 128x64 tile.
// Partial interface unchanged: [bid][64][128] bf16.
// ---------------------------------------------------------------------------
#define SPLITK2 16
#define KPB2    (NK / SPLITK2)   /* 192 */
#define KCH     64

__global__ __launch_bounds__(256)
void k2_ctx(const float* __restrict__ aw,
            const float* __restrict__ v_cache,
            const int* __restrict__ keep_idx,
            __hip_bfloat16* __restrict__ partial)
{
    const int bid = blockIdx.x;          // ((b*8+hkv)*16 + ks)
    const int ks  = bid & 15;
    const int hkv = (bid >> 4) & 7;
    const int b   = bid >> 7;
    const int tid = threadIdx.x;
    const int lane = tid & 63;
    const int w    = tid >> 6;           // wave id -> M rows w*16..+15
    const int fr   = lane & 15;          // fragment row/col
    const int kg   = lane >> 4;          // k-group (8 bf16)

    __shared__ unsigned short Vt[128 * 64];   // 16 KB, swizzled [d][k]
    __shared__ int idxs[KCH];

    const int k0 = ks * KPB2;
    // A row for this lane: global aw row = (b*32 + hkv*4 + w)*16 + fr
    const float* arow = aw + (size_t)((b * HH + hkv * GRP + w) * QQ + fr) * NK + k0;
    const float* vb   = v_cache + (size_t)(b * HKV + hkv) * NN * DD;

    f32x4 acc[8];
#pragma unroll
    for (int nt = 0; nt < 8; ++nt) acc[nt] = (f32x4){0.f, 0.f, 0.f, 0.f};

    // staging assignment: pass p, thread t -> d = t&127, cs = (t>>7) + 2*p
    const int sd  = tid & 127;
    const int sc0 = tid >> 7;

    for (int c = 0; c < KPB2; c += KCH) {
        __syncthreads();                       // Vt free (prev compute done)
        if (tid < KCH) idxs[tid] = keep_idx[k0 + c + tid];
        __syncthreads();                       // idxs ready

        // stage 64 gathered V rows, transposed + swizzled, bf16.
        // Each unit: one (d, 16B-chunk) = 8 k-elements.
#pragma unroll
        for (int p = 0; p < 4; ++p) {
            const int cs = sc0 + 2 * p;        // 16B chunk 0..7 (k = 8cs..8cs+7)
            float v[8];
#pragma unroll
            for (int e = 0; e < 8; ++e)
                v[e] = vb[(size_t)idxs[8 * cs + e] * DD + sd];
            uint4 pk;
            pk.x = pack_bf16(v[0], v[1]);
            pk.y = pack_bf16(v[2], v[3]);
            pk.z = pack_bf16(v[4], v[5]);
            pk.w = pack_bf16(v[6], v[7]);
            const int us = sd * 64 + ((cs ^ (sd & 7)) << 3);
            *reinterpret_cast<uint4*>(&Vt[us]) = pk;
        }
        __syncthreads();                       // Vt ready

        // compute: 2 MFMA k-steps of 32
#pragma unroll
        for (int kc = 0; kc < 2; ++kc) {
            const float* ap = arow + c + kc * 32 + kg * 8;
            const float4 a0 = *reinterpret_cast<const float4*>(ap);
            const float4 a1 = *reinterpret_cast<const float4*>(ap + 4);
            union { bf16x8 v; unsigned int u[4]; } af;
            af.u[0] = pack_bf16(a0.x, a0.y);
            af.u[1] = pack_bf16(a0.z, a0.w);
            af.u[2] = pack_bf16(a1.x, a1.y);
            af.u[3] = pack_bf16(a1.z, a1.w);

            const int cs = kc * 4 + kg;        // 16B chunk index along k
            const int xr = (cs ^ (fr & 7)) << 3;
#pragma unroll
            for (int nt = 0; nt < 8; ++nt) {
                const int d  = nt * 16 + fr;
                const int us = d * 64 + xr;    // (d&7) == (fr&7) since 16|nt*16
                bf16x8 bf = *reinterpret_cast<const bf16x8*>(&Vt[us]);
                acc[nt] = __builtin_amdgcn_mfma_f32_16x16x32_bf16(af.v, bf, acc[nt], 0, 0, 0);
            }
        }
    }

    // epilogue: C/D layout col=lane&15 (d within tile), row=(lane>>4)*4+reg
    __hip_bfloat16* pb = partial + (size_t)bid * (64 * DD);
#pragma unroll
    for (int nt = 0; nt < 8; ++nt) {
#pragma unroll
        for (int reg = 0; reg < 4; ++reg) {
            const int row = w * 16 + kg * 4 + reg;
            pb[row * DD + nt * 16 + fr] = __float2bfloat16(acc[nt][reg]);
        }
    }
}

// ---------------------------------------------------------------------------
// Kernel 3: reduce the 16 bf16 k-split partials into ctx_b[bq][i] (i=h*128+d)
// in BF16 -- the MFMA A-operand layout for k4.
// ---------------------------------------------------------------------------
__global__ __launch_bounds__(256)
void k3_reduce(const __hip_bfloat16* __restrict__ partial,
               __hip_bfloat16* __restrict__ ctxb)
{
    const int flat = blockIdx.x * 256 + threadIdx.x;   // bq*4096 + i
    const int bq = flat >> 12;
    const int i  = flat & 4095;
    const int b = bq >> 4, q = bq & 15;
    const int h = i >> 7,  d = i & 127;
    const int hkv = h >> 2, g = h & 3;
    const int r = g * 16 + q;

    const __hip_bfloat16* p = partial
        + (size_t)((b * 8 + hkv) * SPLITK2) * (64 * DD) + r * DD + d;
    float s = 0.f;
#pragma unroll
    for (int ss = 0; ss < SPLITK2; ++ss)
        s += __bfloat162float(p[(size_t)ss * (64 * DD)]);
    ctxb[flat] = __float2bfloat16(s);
}

// ---------------------------------------------------------------------------
// Kernel 4: out = ctx @ W^T via bf16 MFMA, M=64 x N=4096 x K=4096.
// grid = 128 N-tiles (32 o-cols) * 8 k-splits = 1024 blocks, 256 threads.
// ---------------------------------------------------------------------------
#define K4SPLIT 8
#define K4LEN   (4096 / K4SPLIT)  /* 512 */
#define KC4     128
#define LPAD    136               /* 128 + 8 ushort pad */

__global__ __launch_bounds__(256)
void k4_gemm(const __hip_bfloat16* __restrict__ ctxb,
             const float* __restrict__ W,
             float* __restrict__ pout)
{
    const int nt  = blockIdx.x >> 3;   // 0..127  (o-cols nt*32 .. nt*32+31)
    const int ks  = blockIdx.x & 7;
    const int tid = threadIdx.x;
    const int lane = tid & 63;
    const int w    = tid >> 6;         // wave id: M-rows w*16 .. w*16+15

    __shared__ unsigned short Al[64][LPAD];   // ctx bf16 tile
    __shared__ unsigned short Bl[32][LPAD];   // W   bf16 tile

    f32x4 acc0 = {0.f, 0.f, 0.f, 0.f};
    f32x4 acc1 = {0.f, 0.f, 0.f, 0.f};

    const unsigned short* ctxu = reinterpret_cast<const unsigned short*>(ctxb);
    const int kbase = ks * K4LEN;
    const int fr = lane & 15;          // fragment row/col
    const int kg = lane >> 4;          // k-group (8 bf16 each)

    for (int ch = 0; ch < K4LEN / KC4; ++ch) {
        const int kb = kbase + ch * KC4;
        __syncthreads();

        // stage A: 64 rows x 128 bf16 (16B/thread x 4 passes)
        {
            const int cc = tid & 15;       // 8-ushort chunk within row
            const int r0 = tid >> 4;       // 16 rows per pass
#pragma unroll
            for (int p = 0; p < 4; ++p) {
                const int r = r0 + p * 16;
                float4 v = *reinterpret_cast<const float4*>(
                    ctxu + (size_t)r * 4096 + kb + cc * 8);
                *reinterpret_cast<float4*>(&Al[r][cc * 8]) = v;
            }
        }
        // stage B: 32 rows x 128 f32 -> bf16 (float4/thread x 4 passes)
        {
            const int cc = tid & 31;       // float4 col
            const int r0 = tid >> 5;       // 8 rows per pass
#pragma unroll
            for (int p = 0; p < 4; ++p) {
                const int r = r0 + p * 8;
                float4 v = *reinterpret_cast<const float4*>(
                    W + (size_t)(nt * 32 + r) * 4096 + kb + cc * 4);
                union { ushort4 u; __hip_bfloat16 h[4]; } pk;
                pk.h[0] = __float2bfloat16(v.x);
                pk.h[1] = __float2bfloat16(v.y);
                pk.h[2] = __float2bfloat16(v.z);
                pk.h[3] = __float2bfloat16(v.w);
                *reinterpret_cast<ushort4*>(&Bl[r][cc * 4]) = pk.u;
            }
        }
        __syncthreads();

#pragma unroll
        for (int kst = 0; kst < KC4 / 32; ++kst) {
            const int ko = kst * 32 + kg * 8;
            bf16x8 a  = *reinterpret_cast<const bf16x8*>(&Al[w * 16 + fr][ko]);
            bf16x8 b0 = *reinterpret_cast<const bf16x8*>(&Bl[fr][ko]);
            bf16x8 b1 = *reinterpret_cast<const bf16x8*>(&Bl[16 + fr][ko]);
            acc0 = __builtin_amdgcn_mfma_f32_16x16x32_bf16(a, b0, acc0, 0, 0, 0);
            acc1 = __builtin_amdgcn_mfma_f32_16x16x32_bf16(a, b1, acc1, 0, 0, 0);
        }
    }

    // epilogue: C/D layout col=lane&15, row=(lane>>4)*4+reg
    float* pb = pout + (size_t)ks * (64 * 4096);
#pragma unroll
    for (int reg = 0; reg < 4; ++reg) {
        const int row = w * 16 + kg * 4 + reg;
        pb[(size_t)row * 4096 + nt * 32 + fr]      = acc0[reg];
        pb[(size_t)row * 4096 + nt * 32 + 16 + fr] = acc1[reg];
    }
}

// ---------------------------------------------------------------------------
// Kernel 5: reduce the 8 k-split output partials -> out (output 1).
// ---------------------------------------------------------------------------
__global__ __launch_bounds__(256)
void k5_out(const float* __restrict__ pout, float* __restrict__ out)
{
    const int flat = blockIdx.x * 256 + threadIdx.x;
    float s = 0.f;
#pragma unroll
    for (int ss = 0; ss < K4SPLIT; ++ss)
        s += pout[(size_t)ss * (64 * 4096) + flat];
    out[flat] = s;
}

// ---------------------------------------------------------------------------
extern "C" void kernel_launch(void* const* d_in, const int* in_sizes, int n_in,
                              void* d_out, int out_size, void* d_ws, size_t ws_size,
                              hipStream_t stream)
{
    const float* attn_w  = (const float*)d_in[0];   // [4][32][16][4096]
    const float* v_cache = (const float*)d_in[1];   // [4][8][4096][128]
    const float* o_proj  = (const float*)d_in[2];   // [4096][4096]
    const int*   keep_idx = (const int*)d_in[3];    // [3072]

    float* out    = (float*)d_out;                  // [4][16][4096] = 262144
    float* aw_out = (float*)d_out + 262144;         // [4][32][16][3072] = 6291456

    // ws layout (bytes):
    //   [0, 8 MB)      : k2 bf16 partial (4,194,304 bf16)  -- dead after k3
    //   [0, 8 MB)      : k4 fp32 pout (2,097,152 f32)      -- reuses region
    //   [8 MB, 8.5 MB) : ctx bf16 (262,144 bf16)
    __hip_bfloat16* partial2 = (__hip_bfloat16*)d_ws;
    __hip_bfloat16* ctxb = (__hip_bfloat16*)((char*)d_ws + (size_t)8 * 1024 * 1024);
    float* pout = (float*)d_ws;

    k1_gather_norm<<<BB * HH * QQ, 256, 0, stream>>>(attn_w, keep_idx, aw_out);
    k2_ctx<<<BB * HKV * SPLITK2, 256, 0, stream>>>(aw_out, v_cache, keep_idx, partial2);
    k3_reduce<<<(64 * 4096) / 256, 256, 0, stream>>>(partial2, ctxb);
    k4_gemm<<<128 * K4SPLIT, 256, 0, stream>>>(ctxb, o_proj, pout);
    k5_out<<<(64 * 4096) / 256, 256, 0, stream>>>(pout, out);
}

// Round 6
// 48.545 us; speedup vs baseline: 4.2553x; 1.0070x over previous
//
#include <hip/hip_runtime.h>
#include <hip/hip_bf16.h>

// Problem constants
#define BB   4
#define HH   32
#define QQ   16
#define NN   4096
#define HKV  8
#define DD   128
#define NK   3072
#define GRP  4

typedef __attribute__((ext_vector_type(8))) short bf16x8;
typedef __attribute__((ext_vector_type(4))) float f32x4;

__device__ __forceinline__ unsigned int pack_bf16(float lo, float hi) {
    union { unsigned int u; __hip_bfloat16 h[2]; } p;
    p.h[0] = __float2bfloat16(lo);
    p.h[1] = __float2bfloat16(hi);
    return p.u;
}

// ---------------------------------------------------------------------------
// Kernel 1: gather kept columns of attn_w, renormalize, write aw (output 2)
// in f32 AND a bf16 copy for k2's A-operand (net-zero HBM: +12 MB write here,
// -12 MB read in k2, plus kills k2's A-pack VALU).
// grid = B*H*Q = 2048 blocks, 256 threads.
// ---------------------------------------------------------------------------
__global__ __launch_bounds__(256)
void k1_gather_norm(const float* __restrict__ attn_w,
                    const int* __restrict__ keep_idx,
                    float* __restrict__ aw_out,
                    __hip_bfloat16* __restrict__ aw16)
{
    const int row = blockIdx.x;                 // (b*H + h)*Q + q
    const float* src = attn_w + (size_t)row * NN;
    float* dst = aw_out + (size_t)row * NK;
    unsigned int* dst16 = reinterpret_cast<unsigned int*>(aw16 + (size_t)row * NK);

    __shared__ float vals[NK];
    __shared__ float red[256];

    float s = 0.f;
    for (int k = threadIdx.x; k < NK; k += 256) {
        float v = src[keep_idx[k]];
        vals[k] = v;
        s += v;
    }
    red[threadIdx.x] = s;
    __syncthreads();
    for (int st = 128; st > 0; st >>= 1) {
        if (threadIdx.x < st) red[threadIdx.x] += red[threadIdx.x + st];
        __syncthreads();
    }
    const float inv = 1.0f / (red[0] + 1e-6f);
    for (int k = threadIdx.x * 2; k < NK; k += 512) {
        float a = vals[k] * inv;
        float b = vals[k + 1] * inv;
        *reinterpret_cast<float2*>(&dst[k]) = make_float2(a, b);
        dst16[k >> 1] = pack_bf16(a, b);
    }
}

// ---------------------------------------------------------------------------
// Kernel 2 (v5): ctx partial GEMM via bf16 MFMA, occupancy-doubled.
// grid = B*HKV*SPLITK2 = 512 blocks, 512 threads (8 waves).
// Wave w: mw = w&3 (M rows mw*16..+15), nh = w>>2 (d-half nh*64..+63).
// Both N-halves share the same LDS Vt tile; A (bf16, from k1) read per-wave
// from global (duplicate reads L2-absorbed).
//   B: gathered V staged transposed into LDS Vt[d][k] bf16, XOR chunk swizzle
//      us(d,cs) = d*64 + ((cs ^ (d&7))<<3), cs = 16B chunk (8 k) 0..7.
//      Coverage: unit=(d,cs) -> 128*8 = 1024 units = 2 passes x 512 threads.
// Partial interface unchanged: [bid][64][128] bf16.
// ---------------------------------------------------------------------------
#define SPLITK2 16
#define KPB2    (NK / SPLITK2)   /* 192 */
#define KCH     64

__global__ __launch_bounds__(512, 4)
void k2_ctx(const __hip_bfloat16* __restrict__ aw16,
            const float* __restrict__ v_cache,
            const int* __restrict__ keep_idx,
            __hip_bfloat16* __restrict__ partial)
{
    const int bid = blockIdx.x;          // ((b*8+hkv)*16 + ks)
    const int ks  = bid & 15;
    const int hkv = (bid >> 4) & 7;
    const int b   = bid >> 7;
    const int tid = threadIdx.x;
    const int lane = tid & 63;
    const int w    = tid >> 6;           // wave id 0..7
    const int mw   = w & 3;              // M-group: rows mw*16..+15
    const int nh   = w >> 2;             // d-half: tiles nh*4..nh*4+3
    const int fr   = lane & 15;          // fragment row/col
    const int kg   = lane >> 4;          // k-group (8 bf16)

    __shared__ unsigned short Vt[128 * 64];   // 16 KB, swizzled [d][k]
    __shared__ int idxs[KCH];

    const int k0 = ks * KPB2;
    // A row for this lane: global aw row = (b*32 + hkv*4 + mw)*16 + fr
    const unsigned short* arow = reinterpret_cast<const unsigned short*>(aw16)
        + (size_t)((b * HH + hkv * GRP + mw) * QQ + fr) * NK + k0;
    const float* vb = v_cache + (size_t)(b * HKV + hkv) * NN * DD;

    f32x4 acc[4];
#pragma unroll
    for (int nt = 0; nt < 4; ++nt) acc[nt] = (f32x4){0.f, 0.f, 0.f, 0.f};

    // staging: pass p, thread t -> unit u = t + 512p; d = u&127, cs = u>>7
    const int sd  = tid & 127;
    const int sc0 = tid >> 7;            // 0..3

    for (int c = 0; c < KPB2; c += KCH) {
        __syncthreads();                       // Vt free (prev compute done)
        if (tid < KCH) idxs[tid] = keep_idx[k0 + c + tid];
        __syncthreads();                       // idxs ready

        // stage 64 gathered V rows, transposed + swizzled, bf16.
#pragma unroll
        for (int p = 0; p < 2; ++p) {
            const int cs = sc0 + 4 * p;        // 16B chunk 0..7 (k = 8cs..8cs+7)
            float v[8];
#pragma unroll
            for (int e = 0; e < 8; ++e)
                v[e] = vb[(size_t)idxs[8 * cs + e] * DD + sd];
            uint4 pk;
            pk.x = pack_bf16(v[0], v[1]);
            pk.y = pack_bf16(v[2], v[3]);
            pk.z = pack_bf16(v[4], v[5]);
            pk.w = pack_bf16(v[6], v[7]);
            const int us = sd * 64 + ((cs ^ (sd & 7)) << 3);
            *reinterpret_cast<uint4*>(&Vt[us]) = pk;
        }
        __syncthreads();                       // Vt ready

        // compute: 2 MFMA k-steps of 32, 4 N-tiles (this wave's d-half)
#pragma unroll
        for (int kc = 0; kc < 2; ++kc) {
            bf16x8 af = *reinterpret_cast<const bf16x8*>(arow + c + kc * 32 + kg * 8);
            const int cs = kc * 4 + kg;        // 16B chunk index along k
            const int xr = (cs ^ (fr & 7)) << 3;
#pragma unroll
            for (int nt = 0; nt < 4; ++nt) {
                const int d  = (nh * 4 + nt) * 16 + fr;
                const int us = d * 64 + xr;    // (d&7) == (fr&7)
                bf16x8 bf = *reinterpret_cast<const bf16x8*>(&Vt[us]);
                acc[nt] = __builtin_amdgcn_mfma_f32_16x16x32_bf16(af, bf, acc[nt], 0, 0, 0);
            }
        }
    }

    // epilogue: C/D layout col=lane&15 (d within tile), row=(lane>>4)*4+reg
    __hip_bfloat16* pb = partial + (size_t)bid * (64 * DD);
#pragma unroll
    for (int nt = 0; nt < 4; ++nt) {
#pragma unroll
        for (int reg = 0; reg < 4; ++reg) {
            const int row = mw * 16 + kg * 4 + reg;
            pb[row * DD + (nh * 4 + nt) * 16 + fr] = __float2bfloat16(acc[nt][reg]);
        }
    }
}

// ---------------------------------------------------------------------------
// Kernel 3: reduce the 16 bf16 k-split partials into ctx_b[bq][i] (i=h*128+d)
// in BF16 -- the MFMA A-operand layout for k4.
// ---------------------------------------------------------------------------
__global__ __launch_bounds__(256)
void k3_reduce(const __hip_bfloat16* __restrict__ partial,
               __hip_bfloat16* __restrict__ ctxb)
{
    const int flat = blockIdx.x * 256 + threadIdx.x;   // bq*4096 + i
    const int bq = flat >> 12;
    const int i  = flat & 4095;
    const int b = bq >> 4, q = bq & 15;
    const int h = i >> 7,  d = i & 127;
    const int hkv = h >> 2, g = h & 3;
    const int r = g * 16 + q;

    const __hip_bfloat16* p = partial
        + (size_t)((b * 8 + hkv) * SPLITK2) * (64 * DD) + r * DD + d;
    float s = 0.f;
#pragma unroll
    for (int ss = 0; ss < SPLITK2; ++ss)
        s += __bfloat162float(p[(size_t)ss * (64 * DD)]);
    ctxb[flat] = __float2bfloat16(s);
}

// ---------------------------------------------------------------------------
// Kernel 4: out = ctx @ W^T via bf16 MFMA, M=64 x N=4096 x K=4096.
// grid = 128 N-tiles (32 o-cols) * 8 k-splits = 1024 blocks, 256 threads.
// __launch_bounds__(256,4): cap 128 VGPR -> 4 blocks/CU -> whole grid
// resident in one pass (was 3 blocks/CU -> 1.33 passes).
// pout stored bf16 (-8 MB round-trip).
// ---------------------------------------------------------------------------
#define K4SPLIT 8
#define K4LEN   (4096 / K4SPLIT)  /* 512 */
#define KC4     128
#define LPAD    136               /* 128 + 8 ushort pad */

__global__ __launch_bounds__(256, 4)
void k4_gemm(const __hip_bfloat16* __restrict__ ctxb,
             const float* __restrict__ W,
             __hip_bfloat16* __restrict__ pout)
{
    const int nt  = blockIdx.x >> 3;   // 0..127  (o-cols nt*32 .. nt*32+31)
    const int ks  = blockIdx.x & 7;
    const int tid = threadIdx.x;
    const int lane = tid & 63;
    const int w    = tid >> 6;         // wave id: M-rows w*16 .. w*16+15

    __shared__ unsigned short Al[64][LPAD];   // ctx bf16 tile
    __shared__ unsigned short Bl[32][LPAD];   // W   bf16 tile

    f32x4 acc0 = {0.f, 0.f, 0.f, 0.f};
    f32x4 acc1 = {0.f, 0.f, 0.f, 0.f};

    const unsigned short* ctxu = reinterpret_cast<const unsigned short*>(ctxb);
    const int kbase = ks * K4LEN;
    const int fr = lane & 15;          // fragment row/col
    const int kg = lane >> 4;          // k-group (8 bf16 each)

    for (int ch = 0; ch < K4LEN / KC4; ++ch) {
        const int kb = kbase + ch * KC4;
        __syncthreads();

        // stage A: 64 rows x 128 bf16 (16B/thread x 4 passes)
        {
            const int cc = tid & 15;       // 8-ushort chunk within row
            const int r0 = tid >> 4;       // 16 rows per pass
#pragma unroll
            for (int p = 0; p < 4; ++p) {
                const int r = r0 + p * 16;
                float4 v = *reinterpret_cast<const float4*>(
                    ctxu + (size_t)r * 4096 + kb + cc * 8);
                *reinterpret_cast<float4*>(&Al[r][cc * 8]) = v;
            }
        }
        // stage B: 32 rows x 128 f32 -> bf16 (float4/thread x 4 passes)
        {
            const int cc = tid & 31;       // float4 col
            const int r0 = tid >> 5;       // 8 rows per pass
#pragma unroll
            for (int p = 0; p < 4; ++p) {
                const int r = r0 + p * 8;
                float4 v = *reinterpret_cast<const float4*>(
                    W + (size_t)(nt * 32 + r) * 4096 + kb + cc * 4);
                union { ushort4 u; __hip_bfloat16 h[4]; } pk;
                pk.h[0] = __float2bfloat16(v.x);
                pk.h[1] = __float2bfloat16(v.y);
                pk.h[2] = __float2bfloat16(v.z);
                pk.h[3] = __float2bfloat16(v.w);
                *reinterpret_cast<ushort4*>(&Bl[r][cc * 4]) = pk.u;
            }
        }
        __syncthreads();

#pragma unroll
        for (int kst = 0; kst < KC4 / 32; ++kst) {
            const int ko = kst * 32 + kg * 8;
            bf16x8 a  = *reinterpret_cast<const bf16x8*>(&Al[w * 16 + fr][ko]);
            bf16x8 b0 = *reinterpret_cast<const bf16x8*>(&Bl[fr][ko]);
            bf16x8 b1 = *reinterpret_cast<const bf16x8*>(&Bl[16 + fr][ko]);
            acc0 = __builtin_amdgcn_mfma_f32_16x16x32_bf16(a, b0, acc0, 0, 0, 0);
            acc1 = __builtin_amdgcn_mfma_f32_16x16x32_bf16(a, b1, acc1, 0, 0, 0);
        }
    }

    // epilogue: C/D layout col=lane&15, row=(lane>>4)*4+reg
    __hip_bfloat16* pb = pout + (size_t)ks * (64 * 4096);
#pragma unroll
    for (int reg = 0; reg < 4; ++reg) {
        const int row = w * 16 + kg * 4 + reg;
        pb[(size_t)row * 4096 + nt * 32 + fr]      = __float2bfloat16(acc0[reg]);
        pb[(size_t)row * 4096 + nt * 32 + 16 + fr] = __float2bfloat16(acc1[reg]);
    }
}

// ---------------------------------------------------------------------------
// Kernel 5: reduce the 8 bf16 k-split output partials -> out (output 1).
// ---------------------------------------------------------------------------
__global__ __launch_bounds__(256)
void k5_out(const __hip_bfloat16* __restrict__ pout, float* __restrict__ out)
{
    const int flat = blockIdx.x * 256 + threadIdx.x;
    float s = 0.f;
#pragma unroll
    for (int ss = 0; ss < K4SPLIT; ++ss)
        s += __bfloat162float(pout[(size_t)ss * (64 * 4096) + flat]);
    out[flat] = s;
}

// ---------------------------------------------------------------------------
extern "C" void kernel_launch(void* const* d_in, const int* in_sizes, int n_in,
                              void* d_out, int out_size, void* d_ws, size_t ws_size,
                              hipStream_t stream)
{
    const float* attn_w  = (const float*)d_in[0];   // [4][32][16][4096]
    const float* v_cache = (const float*)d_in[1];   // [4][8][4096][128]
    const float* o_proj  = (const float*)d_in[2];   // [4096][4096]
    const int*   keep_idx = (const int*)d_in[3];    // [3072]

    float* out    = (float*)d_out;                  // [4][16][4096] = 262144
    float* aw_out = (float*)d_out + 262144;         // [4][32][16][3072] = 6291456

    // ws layout (bytes):
    //   [0, 8 MB)       : k2 bf16 partial (4,194,304 bf16) -- dead after k3
    //   [0, 4 MB)       : k4 bf16 pout (2,097,152 bf16)    -- reuses region
    //   [8 MB, 8.5 MB)  : ctx bf16 (262,144 bf16)
    //   [9 MB, 21 MB)   : aw bf16 copy (6,291,456 bf16)
    __hip_bfloat16* partial2 = (__hip_bfloat16*)d_ws;
    __hip_bfloat16* ctxb = (__hip_bfloat16*)((char*)d_ws + (size_t)8 * 1024 * 1024);
    __hip_bfloat16* aw16 = (__hip_bfloat16*)((char*)d_ws + (size_t)9 * 1024 * 1024);
    __hip_bfloat16* pout = (__hip_bfloat16*)d_ws;

    k1_gather_norm<<<BB * HH * QQ, 256, 0, stream>>>(attn_w, keep_idx, aw_out, aw16);
    k2_ctx<<<BB * HKV * SPLITK2, 512, 0, stream>>>(aw16, v_cache, keep_idx, partial2);
    k3_reduce<<<(64 * 4096) / 256, 256, 0, stream>>>(partial2, ctxb);
    k4_gemm<<<128 * K4SPLIT, 256, 0, stream>>>(ctxb, o_proj, pout);
    k5_out<<<(64 * 4096) / 256, 256, 0, stream>>>(pout, out);
}